// Round 6
// baseline (880.133 us; speedup 1.0000x reference)
//
#include <hip/hip_runtime.h>
#include <cstdint>

#define BB 2048
#define NN 128
#define DD 128
#define CHUNK 1024
#define SW 36

// ---------------- threefry2x32 (JAX-exact) ----------------
__device__ __forceinline__ void tf_round(uint32_t& x0, uint32_t& x1, int r) {
  x0 += x1; x1 = (x1 << r) | (x1 >> (32 - r)); x1 ^= x0;
}

__device__ __forceinline__ uint2 threefry(uint32_t k0, uint32_t k1, uint32_t x0, uint32_t x1) {
  uint32_t k2 = k0 ^ k1 ^ 0x1BD11BDAu;
  x0 += k0; x1 += k1;
  tf_round(x0,x1,13); tf_round(x0,x1,15); tf_round(x0,x1,26); tf_round(x0,x1,6);
  x0 += k1; x1 += k2 + 1u;
  tf_round(x0,x1,17); tf_round(x0,x1,29); tf_round(x0,x1,16); tf_round(x0,x1,24);
  x0 += k2; x1 += k0 + 2u;
  tf_round(x0,x1,13); tf_round(x0,x1,15); tf_round(x0,x1,26); tf_round(x0,x1,6);
  x0 += k0; x1 += k1 + 3u;
  tf_round(x0,x1,17); tf_round(x0,x1,29); tf_round(x0,x1,16); tf_round(x0,x1,24);
  x0 += k1; x1 += k2 + 4u;
  tf_round(x0,x1,13); tf_round(x0,x1,15); tf_round(x0,x1,26); tf_round(x0,x1,6);
  x0 += k2; x1 += k0 + 5u;
  uint2 r; r.x = x0; r.y = x1; return r;
}

__device__ __forceinline__ float gumbel_from_bits(uint32_t bits) {
  const float TINY = 1.17549435e-38f;
  float u = __uint_as_float(0x3F800000u | (bits >> 9)) - 1.0f;   // [0,1)
  u = u + TINY;
  u = fmaxf(TINY, u);
  return -logf(-logf(u));   // libm logf: sampling-critical, do not weaken
}

// keys[i] = threefry((0,42),(0,i))
__global__ void k_keys(uint2* __restrict__ keys) {
  int i = threadIdx.x;
  if (i < NN) keys[i] = threefry(0u, 42u, 0u, (uint32_t)i);
}

// M = Wc2 @ Wq   (Wc rows 128..255 are the h_cur part)
__global__ void k_M(const float* __restrict__ Wc, const float* __restrict__ Wq,
                    float* __restrict__ M) {
  __shared__ __align__(16) float wrow[DD];
  int r = blockIdx.x, o = threadIdx.x;
  wrow[o] = Wc[(DD + r) * DD + o];
  __syncthreads();
  float acc = 0.f;
#pragma unroll 4
  for (int c = 0; c < DD; ++c) acc += wrow[c] * Wq[c * DD + o];
  M[r * DD + o] = acc;
}

// Qbase[b] = (graph[b]@Wc1 + bc) @ Wq + bq
__global__ void k_qbase(const float* __restrict__ graph, const float* __restrict__ Wc,
                        const float* __restrict__ bc, const float* __restrict__ Wq,
                        const float* __restrict__ bq, float* __restrict__ Qbase) {
  __shared__ __align__(16) float g[DD];
  __shared__ __align__(16) float c1[DD];
  int b = blockIdx.x, t = threadIdx.x;
  g[t] = graph[b * DD + t];
  __syncthreads();
  float acc = 0.f;
#pragma unroll 4
  for (int r = 0; r < DD; ++r) acc += g[r] * Wc[r * DD + t];
  c1[t] = acc + bc[t];
  __syncthreads();
  float acc2 = 0.f;
#pragma unroll 4
  for (int c = 0; c < DD; ++c) acc2 += c1[c] * Wq[c * DD + t];
  Qbase[b * DD + t] = acc2 + bq[t];
}

// K = h@Wk + bk ; QQ = h@M + Qbase[b]
// 64 rows/block, 512 threads, 4 rows x 4 cols x 2 mats per thread (32 acc).
// (512,2) -> 128-VGPR cap, 4 waves/SIMD. Not spilling (live set ~90).
// Per-element accumulation order over (kp,k4,kk) IDENTICAL to prior version.
__global__ __launch_bounds__(512, 2) void k_kqq(
    const float* __restrict__ h, const float* __restrict__ Wk, const float* __restrict__ bk,
    const float* __restrict__ Mm, const float* __restrict__ Qbase,
    float* __restrict__ Kc, float* __restrict__ QQc, int b0) {
  __shared__ __align__(16) float As[64 * 32];    // 8 KB, swizzled
  __shared__ __align__(16) float Wks[32 * DD];   // 16 KB
  __shared__ __align__(16) float Mms[32 * DD];   // 16 KB
  int tid = threadIdx.x;
  int grow0 = b0 * NN + blockIdx.x * 64;  // global flat row (b*N+n)
  int ty = tid >> 5, tx = tid & 31;       // ty 0..15 (4 rows each), tx 0..31 (4 cols each)
  float accK[4][4] = {{0}}, accQ[4][4] = {{0}};
  for (int kp = 0; kp < DD; kp += 32) {
    __syncthreads();
    {                                                 // h panel 64x32 (1 float4/thread)
      int r = tid >> 3, c4 = (tid & 7) * 4;
      int pc = c4 ^ ((r & 7) * 4);
      *(float4*)&As[r * 32 + pc] = *(const float4*)&h[(size_t)(grow0 + r) * DD + kp + c4];
    }
#pragma unroll
    for (int p = 0; p < 2; ++p) {                     // weight panels 32x128
      int t = tid + p * 512;
      int r = t >> 5, c4 = (t & 31) * 4;
      *(float4*)&Wks[r * DD + c4] = *(const float4*)&Wk[(size_t)(kp + r) * DD + c4];
      *(float4*)&Mms[r * DD + c4] = *(const float4*)&Mm[(size_t)(kp + r) * DD + c4];
    }
    __syncthreads();
#pragma unroll
    for (int k4 = 0; k4 < 32; k4 += 4) {
      float4 a4[4];
#pragma unroll
      for (int i = 0; i < 4; ++i) {
        int row = ty * 4 + i;
        a4[i] = *(const float4*)&As[row * 32 + (k4 ^ ((row & 7) * 4))];
      }
#pragma unroll
      for (int kk = 0; kk < 4; ++kk) {
        float4 w = *(const float4*)&Wks[(k4 + kk) * DD + tx * 4];
        float4 m = *(const float4*)&Mms[(k4 + kk) * DD + tx * 4];
#pragma unroll
        for (int i = 0; i < 4; ++i) {
          float a = ((const float*)&a4[i])[kk];
          accK[i][0] += a * w.x; accK[i][1] += a * w.y; accK[i][2] += a * w.z; accK[i][3] += a * w.w;
          accQ[i][0] += a * m.x; accQ[i][1] += a * m.y; accQ[i][2] += a * m.z; accQ[i][3] += a * m.w;
        }
      }
    }
  }
  float4 bk4 = *(const float4*)&bk[tx * 4];
#pragma unroll
  for (int i = 0; i < 4; ++i) {
    int grow = grow0 + ty * 4 + i;
    int b = grow >> 7;
    int lrow = grow - b0 * NN;
    float4 qb = *(const float4*)&Qbase[b * DD + tx * 4];
    float4 ok, oq;
    ok.x = accK[i][0] + bk4.x; ok.y = accK[i][1] + bk4.y;
    ok.z = accK[i][2] + bk4.z; ok.w = accK[i][3] + bk4.w;
    oq.x = accQ[i][0] + qb.x;  oq.y = accQ[i][1] + qb.y;
    oq.z = accQ[i][2] + qb.z;  oq.w = accQ[i][3] + qb.w;
    *(float4*)&Kc[lrow * DD + tx * 4] = ok;
    *(float4*)&QQc[lrow * DD + tx * 4] = oq;
  }
}

// T[b] = 10*tanh( QQ[b] @ K[b]^T / 32 )
// 512 threads, 4x8 per thread (32 acc), 128-VGPR cap, two scoped 4-wide bv
// groups + unroll-2 keep live regs under 128 (R4: no spill, score left top-5).
// Per-accumulator FMA chain over (kp,k4,kk) UNCHANGED (bit-exact).
__global__ __launch_bounds__(512, 2) void k_score(
    const float* __restrict__ QQc, const float* __restrict__ Kc,
    float* __restrict__ T, int b0) {
  __shared__ __align__(16) float QQs[NN * SW];
  __shared__ __align__(16) float Ks[NN * SW];
  int bb = blockIdx.x;
  int tid = threadIdx.x;
  int ty = tid >> 4, tx = tid & 15;     // ty 0..31 (4 rows each), tx 0..15 (8 cols each)
  const float* QQb = QQc + (size_t)bb * NN * DD;
  const float* Kb  = Kc  + (size_t)bb * NN * DD;
  float acc[4][8] = {{0}};
  for (int kp = 0; kp < DD; kp += 32) {
#pragma unroll
    for (int p = 0; p < 2; ++p) {
      int idx = tid + p * 512;
      int row = idx >> 3, c4 = (idx & 7) * 4;
      int pc = c4 ^ (((row >> 3) & 7) * 4);
      *(float4*)&QQs[row * SW + pc] = *(const float4*)&QQb[row * DD + kp + c4];
      *(float4*)&Ks [row * SW + pc] = *(const float4*)&Kb [row * DD + kp + c4];
    }
    __syncthreads();
#pragma unroll 2
    for (int k4 = 0; k4 < 32; k4 += 4) {
      int ca = k4 ^ (((ty >> 1) & 7) * 4);
      int cb = k4 ^ ((tx & 7) * 4);
      float4 a[4];
#pragma unroll
      for (int i = 0; i < 4; ++i) a[i] = *(const float4*)&QQs[(ty * 4 + i) * SW + ca];
      {                                    // j-group 0..3 (bv live = 4 float4)
        float4 bv[4];
#pragma unroll
        for (int j = 0; j < 4; ++j) bv[j] = *(const float4*)&Ks[(tx * 8 + j) * SW + cb];
#pragma unroll
        for (int i = 0; i < 4; ++i)
#pragma unroll
          for (int j = 0; j < 4; ++j)
            acc[i][j] += a[i].x * bv[j].x + a[i].y * bv[j].y +
                         a[i].z * bv[j].z + a[i].w * bv[j].w;
      }
      {                                    // j-group 4..7
        float4 bv[4];
#pragma unroll
        for (int j = 0; j < 4; ++j) bv[j] = *(const float4*)&Ks[(tx * 8 + 4 + j) * SW + cb];
#pragma unroll
        for (int i = 0; i < 4; ++i)
#pragma unroll
          for (int j = 0; j < 4; ++j)
            acc[i][4 + j] += a[i].x * bv[j].x + a[i].y * bv[j].y +
                             a[i].z * bv[j].z + a[i].w * bv[j].w;
      }
    }
    __syncthreads();
  }
  int b = b0 + bb;
#pragma unroll
  for (int i = 0; i < 4; ++i) {
    int row = ty * 4 + i;
    float4 o0, o1;
    o0.x = 10.0f * tanhf(acc[i][0] * 0.03125f);
    o0.y = 10.0f * tanhf(acc[i][1] * 0.03125f);
    o0.z = 10.0f * tanhf(acc[i][2] * 0.03125f);
    o0.w = 10.0f * tanhf(acc[i][3] * 0.03125f);
    o1.x = 10.0f * tanhf(acc[i][4] * 0.03125f);
    o1.y = 10.0f * tanhf(acc[i][5] * 0.03125f);
    o1.z = 10.0f * tanhf(acc[i][6] * 0.03125f);
    o1.w = 10.0f * tanhf(acc[i][7] * 0.03125f);
    float* dst = &T[((size_t)b * NN + row) * NN + tx * 8];
    *(float4*)dst = o0;
    *(float4*)(dst + 4) = o1;
  }
}

// G[s<<18 | b*128+n] = gumbel(threefry(keys[s], b*128+n)) — bit-identical values.
__global__ __launch_bounds__(256) void k_gumbel(const uint2* __restrict__ keys,
                                                float* __restrict__ G) {
  int idx = blockIdx.x * 256 + threadIdx.x;
  int s = idx >> 18;
  uint32_t cnt = (uint32_t)(idx & ((1 << 18) - 1));
  uint2 k = keys[s];
  uint2 r = threefry(k.x, k.y, 0u, cnt);
  G[idx] = gumbel_from_bits(r.x ^ r.y);
}

// FUSED decode+logp. Lane mapping (lane, lane+64) = k_logp's exact pairing so
// the fused softmax reductions (per-lane combine, butterfly offsets 32..1,
// ascending-s accumulation) are bit-identical to the old k_logp. The argmax is
// an exact max with lowest-index tie-break -> mapping-independent -> same tour.
// logp work (2 expf + logf + 12 shfl) is OFF the serial chain (nothing feeds
// the next step) and executes inside the ~2000-cy cold-T dependent-load stall.
// Deletes the k_logp dispatch and its second 133 MB read of T; pos[] is dead.
__global__ __launch_bounds__(64) void k_decode(
    const float* __restrict__ T, const float* __restrict__ G,
    float* __restrict__ out) {
  int b = blockIdx.x;
  int lane = threadIdx.x;
  bool vis0 = (lane == 0), vis1 = false;   // node lane / node lane+64
  int cur = 0;
  float lp = 0.f;
  if (lane == 0) out[b * NN] = 0.0f;
  const float* Tb = T + (size_t)b * NN * NN;
  const float* Gb = G + (size_t)b * NN;
  float gn0 = Gb[lane];                    // step-0 gumbels
  float gn1 = Gb[lane + 64];
  for (int s = 0; s < NN - 1; ++s) {
    float g0 = gn0, g1 = gn1;
    int sn = (s + 1 < NN - 1) ? s + 1 : s;
    gn0 = Gb[((size_t)sn << 18) + lane];        // independent prefetch
    gn1 = Gb[((size_t)sn << 18) + lane + 64];
    float sc0 = Tb[cur * NN + lane];            // dependent load (serial path)
    float sc1 = Tb[cur * NN + lane + 64];
    bool u0 = !vis0, u1 = !vis1;                // unvisited at step s
    // ---- argmax (serial path) ----
    float v0 = vis0 ? -INFINITY : sc0 + g0;
    float v1 = vis1 ? -INFINITY : sc1 + g1;
    float bvv; int bi;
    if (v1 > v0) { bvv = v1; bi = lane + 64; } else { bvv = v0; bi = lane; }
#pragma unroll
    for (int off = 32; off > 0; off >>= 1) {
      float ov = __shfl_xor(bvv, off);
      int oi = __shfl_xor(bi, off);
      if (ov > bvv || (ov == bvv && oi < bi)) { bvv = ov; bi = oi; }
    }
    int nxt = bi;
    // ---- logp (independent of next step; hides under the load stall) ----
    {
      int sel = (nxt >> 6) & 1;
      float xx = sel ? sc1 : sc0;
      float scn = __shfl(xx, nxt & 63);         // T[cur][nxt], uniform
      float m = fmaxf(u0 ? sc0 : -INFINITY, u1 ? sc1 : -INFINITY);
#pragma unroll
      for (int off = 32; off > 0; off >>= 1) m = fmaxf(m, __shfl_xor(m, off));
      float e = (u0 ? expf(sc0 - m) : 0.f) + (u1 ? expf(sc1 - m) : 0.f);
#pragma unroll
      for (int off = 32; off > 0; off >>= 1) e += __shfl_xor(e, off);
      lp += scn - m - logf(e);                  // ascending s: same order as k_logp
    }
    // ---- state update ----
    cur = nxt;
    vis0 = vis0 || (lane == nxt);
    vis1 = vis1 || (lane + 64 == nxt);
    if (lane == 0) out[b * NN + s + 1] = (float)cur;
  }
  if (lane == 0) out[BB * NN + b] = lp;
}

extern "C" void kernel_launch(void* const* d_in, const int* in_sizes, int n_in,
                              void* d_out, int out_size, void* d_ws, size_t ws_size,
                              hipStream_t stream) {
  const float* h     = (const float*)d_in[0];
  const float* graph = (const float*)d_in[1];
  const float* Wq    = (const float*)d_in[2];
  const float* bq    = (const float*)d_in[3];
  const float* Wk    = (const float*)d_in[4];
  const float* bk    = (const float*)d_in[5];
  const float* Wc    = (const float*)d_in[8];
  const float* bc    = (const float*)d_in[9];
  float* out = (float*)d_out;

  char* ws = (char*)d_ws;
  uint2* keys  = (uint2*)ws;                        // 1 KB
  float* Mm    = (float*)(ws + 1024);               // 64 KB
  float* Qbase = (float*)(ws + 66560);              // 1 MB
  float* T     = (float*)(ws + (size_t)(4 << 20));  // 134.2 MB
  // X region (134.2 MB): Kc/QQc during the chunk loop, then G overwrites it (dead).
  size_t xoff  = (size_t)(4 << 20) + (size_t)BB * NN * NN * 4;
  float* Kc    = (float*)(ws + xoff);                                   // 67.1 MB
  float* QQc   = (float*)(ws + xoff + (size_t)CHUNK * NN * DD * 4);     // 67.1 MB
  float* G     = (float*)(ws + xoff);                                   // 133.6 MB

  k_keys<<<1, 128, 0, stream>>>(keys);
  k_M<<<128, 128, 0, stream>>>(Wc, Wq, Mm);
  k_qbase<<<BB, 128, 0, stream>>>(graph, Wc, bc, Wq, bq, Qbase);
  for (int b0 = 0; b0 < BB; b0 += CHUNK) {
    k_kqq<<<CHUNK * NN / 64, 512, 0, stream>>>(h, Wk, bk, Mm, Qbase, Kc, QQc, b0);
    k_score<<<CHUNK, 512, 0, stream>>>(QQc, Kc, T, b0);
  }
  k_gumbel<<<127 * 1024, 256, 0, stream>>>(keys, G);   // overwrites Kc/QQc (dead)
  k_decode<<<BB, 64, 0, stream>>>(T, G, out);
}

// Round 8
// 826.371 us; speedup vs baseline: 1.0651x; 1.0651x over previous
//
#include <hip/hip_runtime.h>
#include <cstdint>

#define BB 2048
#define NN 128
#define DD 128
#define CHUNK 1024
#define SW 36

// ---------------- threefry2x32 (JAX-exact) ----------------
__device__ __forceinline__ void tf_round(uint32_t& x0, uint32_t& x1, int r) {
  x0 += x1; x1 = (x1 << r) | (x1 >> (32 - r)); x1 ^= x0;
}

__device__ __forceinline__ uint2 threefry(uint32_t k0, uint32_t k1, uint32_t x0, uint32_t x1) {
  uint32_t k2 = k0 ^ k1 ^ 0x1BD11BDAu;
  x0 += k0; x1 += k1;
  tf_round(x0,x1,13); tf_round(x0,x1,15); tf_round(x0,x1,26); tf_round(x0,x1,6);
  x0 += k1; x1 += k2 + 1u;
  tf_round(x0,x1,17); tf_round(x0,x1,29); tf_round(x0,x1,16); tf_round(x0,x1,24);
  x0 += k2; x1 += k0 + 2u;
  tf_round(x0,x1,13); tf_round(x0,x1,15); tf_round(x0,x1,26); tf_round(x0,x1,6);
  x0 += k0; x1 += k1 + 3u;
  tf_round(x0,x1,17); tf_round(x0,x1,29); tf_round(x0,x1,16); tf_round(x0,x1,24);
  x0 += k1; x1 += k2 + 4u;
  tf_round(x0,x1,13); tf_round(x0,x1,15); tf_round(x0,x1,26); tf_round(x0,x1,6);
  x0 += k2; x1 += k0 + 5u;
  uint2 r; r.x = x0; r.y = x1; return r;
}

__device__ __forceinline__ float gumbel_from_bits(uint32_t bits) {
  const float TINY = 1.17549435e-38f;
  float u = __uint_as_float(0x3F800000u | (bits >> 9)) - 1.0f;   // [0,1)
  u = u + TINY;
  u = fmaxf(TINY, u);
  return -logf(-logf(u));   // libm logf: sampling-critical, do not weaken
}

// keys[i] = threefry((0,42),(0,i))
__global__ void k_keys(uint2* __restrict__ keys) {
  int i = threadIdx.x;
  if (i < NN) keys[i] = threefry(0u, 42u, 0u, (uint32_t)i);
}

// M = Wc2 @ Wq   (Wc rows 128..255 are the h_cur part)
__global__ void k_M(const float* __restrict__ Wc, const float* __restrict__ Wq,
                    float* __restrict__ M) {
  __shared__ __align__(16) float wrow[DD];
  int r = blockIdx.x, o = threadIdx.x;
  wrow[o] = Wc[(DD + r) * DD + o];
  __syncthreads();
  float acc = 0.f;
#pragma unroll 4
  for (int c = 0; c < DD; ++c) acc += wrow[c] * Wq[c * DD + o];
  M[r * DD + o] = acc;
}

// Qbase[b] = (graph[b]@Wc1 + bc) @ Wq + bq
__global__ void k_qbase(const float* __restrict__ graph, const float* __restrict__ Wc,
                        const float* __restrict__ bc, const float* __restrict__ Wq,
                        const float* __restrict__ bq, float* __restrict__ Qbase) {
  __shared__ __align__(16) float g[DD];
  __shared__ __align__(16) float c1[DD];
  int b = blockIdx.x, t = threadIdx.x;
  g[t] = graph[b * DD + t];
  __syncthreads();
  float acc = 0.f;
#pragma unroll 4
  for (int r = 0; r < DD; ++r) acc += g[r] * Wc[r * DD + t];
  c1[t] = acc + bc[t];
  __syncthreads();
  float acc2 = 0.f;
#pragma unroll 4
  for (int c = 0; c < DD; ++c) acc2 += c1[c] * Wq[c * DD + t];
  Qbase[b * DD + t] = acc2 + bq[t];
}

// K = h@Wk + bk ; QQ = h@M + Qbase[b]
// 64 rows/block, 512 threads, 4 rows x 4 cols x 2 mats per thread (32 acc).
// (512,2) -> 128-VGPR cap, 4 waves/SIMD. Not spilling (live set ~90).
// Per-element accumulation order over (kp,k4,kk) IDENTICAL to prior version.
__global__ __launch_bounds__(512, 2) void k_kqq(
    const float* __restrict__ h, const float* __restrict__ Wk, const float* __restrict__ bk,
    const float* __restrict__ Mm, const float* __restrict__ Qbase,
    float* __restrict__ Kc, float* __restrict__ QQc, int b0) {
  __shared__ __align__(16) float As[64 * 32];    // 8 KB, swizzled
  __shared__ __align__(16) float Wks[32 * DD];   // 16 KB
  __shared__ __align__(16) float Mms[32 * DD];   // 16 KB
  int tid = threadIdx.x;
  int grow0 = b0 * NN + blockIdx.x * 64;  // global flat row (b*N+n)
  int ty = tid >> 5, tx = tid & 31;       // ty 0..15 (4 rows each), tx 0..31 (4 cols each)
  float accK[4][4] = {{0}}, accQ[4][4] = {{0}};
  for (int kp = 0; kp < DD; kp += 32) {
    __syncthreads();
    {                                                 // h panel 64x32 (1 float4/thread)
      int r = tid >> 3, c4 = (tid & 7) * 4;
      int pc = c4 ^ ((r & 7) * 4);
      *(float4*)&As[r * 32 + pc] = *(const float4*)&h[(size_t)(grow0 + r) * DD + kp + c4];
    }
#pragma unroll
    for (int p = 0; p < 2; ++p) {                     // weight panels 32x128
      int t = tid + p * 512;
      int r = t >> 5, c4 = (t & 31) * 4;
      *(float4*)&Wks[r * DD + c4] = *(const float4*)&Wk[(size_t)(kp + r) * DD + c4];
      *(float4*)&Mms[r * DD + c4] = *(const float4*)&Mm[(size_t)(kp + r) * DD + c4];
    }
    __syncthreads();
#pragma unroll
    for (int k4 = 0; k4 < 32; k4 += 4) {
      float4 a4[4];
#pragma unroll
      for (int i = 0; i < 4; ++i) {
        int row = ty * 4 + i;
        a4[i] = *(const float4*)&As[row * 32 + (k4 ^ ((row & 7) * 4))];
      }
#pragma unroll
      for (int kk = 0; kk < 4; ++kk) {
        float4 w = *(const float4*)&Wks[(k4 + kk) * DD + tx * 4];
        float4 m = *(const float4*)&Mms[(k4 + kk) * DD + tx * 4];
#pragma unroll
        for (int i = 0; i < 4; ++i) {
          float a = ((const float*)&a4[i])[kk];
          accK[i][0] += a * w.x; accK[i][1] += a * w.y; accK[i][2] += a * w.z; accK[i][3] += a * w.w;
          accQ[i][0] += a * m.x; accQ[i][1] += a * m.y; accQ[i][2] += a * m.z; accQ[i][3] += a * m.w;
        }
      }
    }
  }
  float4 bk4 = *(const float4*)&bk[tx * 4];
#pragma unroll
  for (int i = 0; i < 4; ++i) {
    int grow = grow0 + ty * 4 + i;
    int b = grow >> 7;
    int lrow = grow - b0 * NN;
    float4 qb = *(const float4*)&Qbase[b * DD + tx * 4];
    float4 ok, oq;
    ok.x = accK[i][0] + bk4.x; ok.y = accK[i][1] + bk4.y;
    ok.z = accK[i][2] + bk4.z; ok.w = accK[i][3] + bk4.w;
    oq.x = accQ[i][0] + qb.x;  oq.y = accQ[i][1] + qb.y;
    oq.z = accQ[i][2] + qb.z;  oq.w = accQ[i][3] + qb.w;
    *(float4*)&Kc[lrow * DD + tx * 4] = ok;
    *(float4*)&QQc[lrow * DD + tx * 4] = oq;
  }
}

// T[b] = 10*tanh( QQ[b] @ K[b]^T / 32 )
// 512 threads, 4x8 per thread (32 acc), 128-VGPR cap, two scoped 4-wide bv
// groups + unroll-2 keep live regs under 128 (R4: no spill, score left top-5).
// Per-accumulator FMA chain over (kp,k4,kk) UNCHANGED (bit-exact).
__global__ __launch_bounds__(512, 2) void k_score(
    const float* __restrict__ QQc, const float* __restrict__ Kc,
    float* __restrict__ T, int b0) {
  __shared__ __align__(16) float QQs[NN * SW];
  __shared__ __align__(16) float Ks[NN * SW];
  int bb = blockIdx.x;
  int tid = threadIdx.x;
  int ty = tid >> 4, tx = tid & 15;     // ty 0..31 (4 rows each), tx 0..15 (8 cols each)
  const float* QQb = QQc + (size_t)bb * NN * DD;
  const float* Kb  = Kc  + (size_t)bb * NN * DD;
  float acc[4][8] = {{0}};
  for (int kp = 0; kp < DD; kp += 32) {
#pragma unroll
    for (int p = 0; p < 2; ++p) {
      int idx = tid + p * 512;
      int row = idx >> 3, c4 = (idx & 7) * 4;
      int pc = c4 ^ (((row >> 3) & 7) * 4);
      *(float4*)&QQs[row * SW + pc] = *(const float4*)&QQb[row * DD + kp + c4];
      *(float4*)&Ks [row * SW + pc] = *(const float4*)&Kb [row * DD + kp + c4];
    }
    __syncthreads();
#pragma unroll 2
    for (int k4 = 0; k4 < 32; k4 += 4) {
      int ca = k4 ^ (((ty >> 1) & 7) * 4);
      int cb = k4 ^ ((tx & 7) * 4);
      float4 a[4];
#pragma unroll
      for (int i = 0; i < 4; ++i) a[i] = *(const float4*)&QQs[(ty * 4 + i) * SW + ca];
      {                                    // j-group 0..3 (bv live = 4 float4)
        float4 bv[4];
#pragma unroll
        for (int j = 0; j < 4; ++j) bv[j] = *(const float4*)&Ks[(tx * 8 + j) * SW + cb];
#pragma unroll
        for (int i = 0; i < 4; ++i)
#pragma unroll
          for (int j = 0; j < 4; ++j)
            acc[i][j] += a[i].x * bv[j].x + a[i].y * bv[j].y +
                         a[i].z * bv[j].z + a[i].w * bv[j].w;
      }
      {                                    // j-group 4..7
        float4 bv[4];
#pragma unroll
        for (int j = 0; j < 4; ++j) bv[j] = *(const float4*)&Ks[(tx * 8 + 4 + j) * SW + cb];
#pragma unroll
        for (int i = 0; i < 4; ++i)
#pragma unroll
          for (int j = 0; j < 4; ++j)
            acc[i][4 + j] += a[i].x * bv[j].x + a[i].y * bv[j].y +
                             a[i].z * bv[j].z + a[i].w * bv[j].w;
      }
    }
    __syncthreads();
  }
  int b = b0 + bb;
#pragma unroll
  for (int i = 0; i < 4; ++i) {
    int row = ty * 4 + i;
    float4 o0, o1;
    o0.x = 10.0f * tanhf(acc[i][0] * 0.03125f);
    o0.y = 10.0f * tanhf(acc[i][1] * 0.03125f);
    o0.z = 10.0f * tanhf(acc[i][2] * 0.03125f);
    o0.w = 10.0f * tanhf(acc[i][3] * 0.03125f);
    o1.x = 10.0f * tanhf(acc[i][4] * 0.03125f);
    o1.y = 10.0f * tanhf(acc[i][5] * 0.03125f);
    o1.z = 10.0f * tanhf(acc[i][6] * 0.03125f);
    o1.w = 10.0f * tanhf(acc[i][7] * 0.03125f);
    float* dst = &T[((size_t)b * NN + row) * NN + tx * 8];
    *(float4*)dst = o0;
    *(float4*)(dst + 4) = o1;
  }
}

// G[s<<18 | b*128+n] = gumbel(threefry(keys[s], b*128+n)) — bit-identical values.
__global__ __launch_bounds__(256) void k_gumbel(const uint2* __restrict__ keys,
                                                float* __restrict__ G) {
  int idx = blockIdx.x * 256 + threadIdx.x;
  int s = idx >> 18;
  uint32_t cnt = (uint32_t)(idx & ((1 << 18) - 1));
  uint2 k = keys[s];
  uint2 r = threefry(k.x, k.y, 0u, cnt);
  G[idx] = gumbel_from_bits(r.x ^ r.y);
}

// FUSED decode+logp, SOFTWARE-PIPELINED.
// R6 post-mortem: logp sat between the butterfly and the NEXT dependent T-load
// in program order -> serial chain = load + argmax + logp (+49 µs). Fix: issue
// step s+1's T-row + G loads immediately after nxt is known, THEN do step s's
// logp from registers — logp now executes inside the load-latency window.
// Arithmetic identical to R6 (absmax 0.0 verified); only issue order changed.
__global__ __launch_bounds__(64) void k_decode(
    const float* __restrict__ T, const float* __restrict__ G,
    float* __restrict__ out) {
  int b = blockIdx.x;
  int lane = threadIdx.x;
  bool vis0 = (lane == 0), vis1 = false;   // node lane / node lane+64
  int cur = 0;
  float lp = 0.f;
  if (lane == 0) out[b * NN] = 0.0f;
  const float* Tb = T + (size_t)b * NN * NN;
  const float* Gb = G + (size_t)b * NN;
  float g0 = Gb[lane];                     // step-0 gumbels
  float g1 = Gb[lane + 64];
  float sc0 = Tb[lane];                    // row cur=0 (prologue)
  float sc1 = Tb[lane + 64];
  for (int s = 0; s < NN - 1; ++s) {
    bool u0 = !vis0, u1 = !vis1;           // unvisited at step s
    // ---- argmax (serial path) ----
    float v0 = vis0 ? -INFINITY : sc0 + g0;
    float v1 = vis1 ? -INFINITY : sc1 + g1;
    float bvv; int bi;
    if (v1 > v0) { bvv = v1; bi = lane + 64; } else { bvv = v0; bi = lane; }
#pragma unroll
    for (int off = 32; off > 0; off >>= 1) {
      float ov = __shfl_xor(bvv, off);
      int oi = __shfl_xor(bi, off);
      if (ov > bvv || (ov == bvv && oi < bi)) { bvv = ov; bi = oi; }
    }
    int nxt = bi;
    // ---- issue step s+1 loads NOW (address needs only nxt) ----
    int sn = (s + 1 < NN - 1) ? s + 1 : s;
    float nsc0 = Tb[nxt * NN + lane];           // dependent, in flight during logp
    float nsc1 = Tb[nxt * NN + lane + 64];
    float ng0 = Gb[((size_t)sn << 18) + lane];  // independent prefetch
    float ng1 = Gb[((size_t)sn << 18) + lane + 64];
    // ---- logp for step s (registers only; hides under the loads) ----
    {
      int sel = (nxt >> 6) & 1;
      float xx = sel ? sc1 : sc0;
      float scn = __shfl(xx, nxt & 63);         // T[cur][nxt], uniform
      float m = fmaxf(u0 ? sc0 : -INFINITY, u1 ? sc1 : -INFINITY);
#pragma unroll
      for (int off = 32; off > 0; off >>= 1) m = fmaxf(m, __shfl_xor(m, off));
      float e = (u0 ? expf(sc0 - m) : 0.f) + (u1 ? expf(sc1 - m) : 0.f);
#pragma unroll
      for (int off = 32; off > 0; off >>= 1) e += __shfl_xor(e, off);
      lp += scn - m - logf(e);                  // ascending s: same order as before
    }
    // ---- state update ----
    cur = nxt;
    vis0 = vis0 || (lane == nxt);
    vis1 = vis1 || (lane + 64 == nxt);
    if (lane == 0) out[b * NN + s + 1] = (float)cur;
    sc0 = nsc0; sc1 = nsc1; g0 = ng0; g1 = ng1;
  }
  if (lane == 0) out[BB * NN + b] = lp;
}

extern "C" void kernel_launch(void* const* d_in, const int* in_sizes, int n_in,
                              void* d_out, int out_size, void* d_ws, size_t ws_size,
                              hipStream_t stream) {
  const float* h     = (const float*)d_in[0];
  const float* graph = (const float*)d_in[1];
  const float* Wq    = (const float*)d_in[2];
  const float* bq    = (const float*)d_in[3];
  const float* Wk    = (const float*)d_in[4];
  const float* bk    = (const float*)d_in[5];
  const float* Wc    = (const float*)d_in[8];
  const float* bc    = (const float*)d_in[9];
  float* out = (float*)d_out;

  char* ws = (char*)d_ws;
  uint2* keys  = (uint2*)ws;                        // 1 KB
  float* Mm    = (float*)(ws + 1024);               // 64 KB
  float* Qbase = (float*)(ws + 66560);              // 1 MB
  float* T     = (float*)(ws + (size_t)(4 << 20));  // 134.2 MB
  // X region (134.2 MB): Kc/QQc during the chunk loop, then G overwrites it (dead).
  size_t xoff  = (size_t)(4 << 20) + (size_t)BB * NN * NN * 4;
  float* Kc    = (float*)(ws + xoff);                                   // 67.1 MB
  float* QQc   = (float*)(ws + xoff + (size_t)CHUNK * NN * DD * 4);     // 67.1 MB
  float* G     = (float*)(ws + xoff);                                   // 133.6 MB

  k_keys<<<1, 128, 0, stream>>>(keys);
  k_M<<<128, 128, 0, stream>>>(Wc, Wq, Mm);
  k_qbase<<<BB, 128, 0, stream>>>(graph, Wc, bc, Wq, bq, Qbase);
  for (int b0 = 0; b0 < BB; b0 += CHUNK) {
    k_kqq<<<CHUNK * NN / 64, 512, 0, stream>>>(h, Wk, bk, Mm, Qbase, Kc, QQc, b0);
    k_score<<<CHUNK, 512, 0, stream>>>(QQc, Kc, T, b0);
  }
  k_gumbel<<<127 * 1024, 256, 0, stream>>>(keys, G);   // overwrites Kc/QQc (dead)
  k_decode<<<BB, 64, 0, stream>>>(T, G, out);
}